// Round 21
// baseline (3111.342 us; speedup 1.0000x reference)
//
#include <hip/hip_runtime.h>
#include <math.h>

#define B_SZ 32
#define T_SZ 2048
#define DIN 256
#define DH 256
#define FOUR_D 1024

// 8 WGs per batch, 512 threads; thread -> (dd=tid>>4, gate=(tid>>2)&3, seg=tid&3)
// Waves 0-3 (tid<256): pure pollers. Waves 4-7: shadow-compute producers.
#define NW 8

// padded f16 index: +8 f16 (16B) per 64-elem block
#define IK16(k) ((k) + ((k) >> 6) * 8)
// weight-LDS row stride in f16 elems (264*2=528B -> bank shift 4/row)
#define USTR 264

typedef _Float16 f16x2 __attribute__((ext_vector_type(2)));

#if __has_builtin(__builtin_amdgcn_fdot2)
#define FDOT2(a, b, c) __builtin_amdgcn_fdot2((a), (b), (c), false)
#else
__device__ __forceinline__ float fdot2_emu(f16x2 a, f16x2 b, float c) {
    return c + (float)a[0] * (float)b[0] + (float)a[1] * (float)b[1];
}
#define FDOT2(a, b, c) fdot2_emu((a), (b), (c))
#endif

__device__ __forceinline__ f16x2 H2(float f) {
    union { float f; f16x2 h; } u; u.f = f; return u.h;
}

__global__ void zero_ws(unsigned int* p, int n) {
    int i = blockIdx.x * blockDim.x + threadIdx.x;
    if (i < n) p[i] = 0u;
}

// Fully-fused single-launch LSTM (R20) + producer/consumer wave split:
//  - waves 0-3: poll IMMEDIATELY each step (first load ~20cy after B-exit,
//    not after the x-stash+W-GEMV block) -> discovery starts earlier.
//  - waves 4-7: x staging + BOTH W-partials (own + front partner's; partner
//    = tid-256 shares gate/seg -> same x window, 8 shared b128 reads).
//    Partner partial via parity-dbuf wacc LDS; own kept in register.
//  - U/W slices in pinned regs (uq / wqo+wqp); LDS steady-state traffic is
//    pure broadcast + wacc b32 (2-way, free).
__global__ __launch_bounds__(512, 2) void lstm_fused6(
    const float* __restrict__ x, const float* __restrict__ W,
    const float* __restrict__ U, const float* __restrict__ bias,
    float* __restrict__ out, unsigned long long* __restrict__ hbuf)
{
    __shared__ _Float16 u_lds[128 * USTR];   // 67.6 KB f16 U-slice (staging)
    __shared__ _Float16 w_lds[128 * USTR];   // 67.6 KB f16 W-slice (staging)
    __shared__ _Float16 h1_lds[2][288];      // padded f16 h, parity dbuf
    __shared__ _Float16 x_lds[2][288];       // padded f16 x row, parity dbuf
    __shared__ float    wacc[2][256];        // front threads' W-partials

    const int b = blockIdx.x >> 3;     // batch (batch-contiguous)
    const int w = blockIdx.x & 7;      // WG-within-batch
    const int tid = threadIdx.x;
    const int dd = tid >> 4;           // dim within WG: 0..31
    const int gate = (tid >> 2) & 3;   // 0..3
    const int seg = tid & 3;           // K-segment: 0..3 (64 k each)
    const int colg = (gate << 8) + (w << 5) + dd;   // global preact column
    const int d = (w << 5) + dd;       // global dim of this 16-lane group
    const bool pub = (tid & 15) == 0;  // publisher lane for dim d
    const bool back = (tid >= 256);    // producer waves

    // partner (front) indices for back threads: same gate/seg, dd-16
    const int dd_par = (dd - 16) & 31;
    const int colg_par = (gate << 8) + (w << 5) + dd_par;

    // ---- prologue: stage U and W slices to LDS as f16 (derived layout)
    for (int it = 0; it < 64; ++it) {
        int lin = (it << 9) + tid;          // 0..32767
        int row = lin & 127;                // = dd*4 + gate
        int kk = lin >> 7;                  // 0..255
        int gcol = ((row & 3) << 8) + (w << 5) + (row >> 2);
        int sg = kk >> 6;
        int cc = (kk >> 3) & 7;
        int jj = kk & 7;
        int p = ((cc >> 1) << 3) + (sg << 1) + (cc & 1);
        int idx = row * USTR + (p << 3) + jj;
        u_lds[idx] = (_Float16)U[(size_t)kk * FOUR_D + gcol];
        w_lds[idx] = (_Float16)W[(size_t)kk * FOUR_D + gcol];
    }
    // x row 0 -> x_lds[0]; x row 1 -> prefetch regs (staging crew: tids 448+)
    float4 xr = make_float4(0.f, 0.f, 0.f, 0.f);
    if (tid >= 448) {
        int l = tid - 448;
        float4 v0 = *(const float4*)&x[((size_t)b * T_SZ) * DIN + l * 4];
        _Float16* dst = &x_lds[0][IK16(l * 4)];
        dst[0] = (_Float16)v0.x; dst[1] = (_Float16)v0.y;
        dst[2] = (_Float16)v0.z; dst[3] = (_Float16)v0.w;
        xr = *(const float4*)&x[((size_t)b * T_SZ + 1) * DIN + l * 4];
    }
    const float binit_own = (seg == 0) ? bias[colg] : 0.0f;
    const float binit_par = (seg == 0) ? bias[colg_par] : 0.0f;
    float c_reg = 0.0f;
    __syncthreads();   // u_lds / w_lds / x_lds[0] ready

    // ---- one-time: U chunks (all threads) and W chunk pairs (back only)
    const int rowb = (dd * 4 + gate) * USTR;
    float4 uq[8], wqo[8], wqp[8];
#pragma unroll
    for (int c2 = 0; c2 < 8; ++c2) {
        int p = ((c2 >> 1) << 3) + (seg << 1) + (c2 & 1);
        uq[c2] = *(const float4*)&u_lds[rowb + (p << 3)];
    }
#pragma unroll
    for (int c2 = 0; c2 < 8; ++c2) {
        asm volatile("" : "+v"(uq[c2].x), "+v"(uq[c2].y),
                          "+v"(uq[c2].z), "+v"(uq[c2].w));
    }
    if (back) {
        const int rowb_par = (dd_par * 4 + gate) * USTR;
#pragma unroll
        for (int c2 = 0; c2 < 8; ++c2) {
            int p = ((c2 >> 1) << 3) + (seg << 1) + (c2 & 1);
            wqo[c2] = *(const float4*)&w_lds[rowb + (p << 3)];
            wqp[c2] = *(const float4*)&w_lds[rowb_par + (p << 3)];
        }
#pragma unroll
        for (int c2 = 0; c2 < 8; ++c2) {
            asm volatile("" : "+v"(wqo[c2].x), "+v"(wqo[c2].y),
                              "+v"(wqo[c2].z), "+v"(wqo[c2].w));
            asm volatile("" : "+v"(wqp[c2].x), "+v"(wqp[c2].y),
                              "+v"(wqp[c2].z), "+v"(wqp[c2].w));
        }
    }

    for (int tt = 0; tt < T_SZ; ++tt) {
        float wown = 0.0f;

        if (back) {
            // --- producer waves: x staging + both W-partials (poll shadow)
            if (tid >= 448) {
                int l = tid - 448;
                if (tt + 1 < T_SZ) {
                    _Float16* dst = &x_lds[(tt + 1) & 1][IK16(l * 4)];
                    dst[0] = (_Float16)xr.x; dst[1] = (_Float16)xr.y;
                    dst[2] = (_Float16)xr.z; dst[3] = (_Float16)xr.w;
                }
                if (tt + 2 < T_SZ)
                    xr = *(const float4*)&x[((size_t)b * T_SZ + tt + 2) * DIN + l * 4];
            }
            const _Float16* xrow = &x_lds[tt & 1][seg * 72];
            float a0 = binit_own, a1 = 0.f, a2 = 0.f, a3 = 0.f;
            float b0 = binit_par, b1 = 0.f, b2 = 0.f, b3 = 0.f;
#pragma unroll
            for (int c2 = 0; c2 < 8; ++c2) {
                float4 xv = *(const float4*)&xrow[c2 << 3];
                a0 = FDOT2(H2(wqo[c2].x), H2(xv.x), a0);
                a1 = FDOT2(H2(wqo[c2].y), H2(xv.y), a1);
                a2 = FDOT2(H2(wqo[c2].z), H2(xv.z), a2);
                a3 = FDOT2(H2(wqo[c2].w), H2(xv.w), a3);
                b0 = FDOT2(H2(wqp[c2].x), H2(xv.x), b0);
                b1 = FDOT2(H2(wqp[c2].y), H2(xv.y), b1);
                b2 = FDOT2(H2(wqp[c2].z), H2(xv.z), b2);
                b3 = FDOT2(H2(wqp[c2].w), H2(xv.w), b3);
            }
            wown = (a0 + a1) + (a2 + a3);
            wacc[tt & 1][tid - 256] = (b0 + b1) + (b2 + b3);
        } else {
            // --- poller waves: poll IMMEDIATELY (nothing precedes the spin)
            const bool local = (tid >> 5) == w;
            if (tt == 0) {
                h1_lds[0][IK16(tid)] = (_Float16)0.0f;
            } else if (!local) {
                const unsigned long long want = (unsigned long long)(unsigned)tt;
                const unsigned long long* slot = hbuf +
                    (((size_t)(tt & 1) * B_SZ + b) * DH + tid);
                unsigned long long v;
                do {
                    v = __hip_atomic_load(slot, __ATOMIC_RELAXED,
                                          __HIP_MEMORY_SCOPE_AGENT);
                } while ((v >> 32) != want);
                h1_lds[tt & 1][IK16(tid)] = (_Float16)__uint_as_float((unsigned)v);
            }
        }
        __syncthreads();   // B1 (only barrier): h + x stash + wacc ready

        // --- U-GEMV from pinned registers; W-partial from wacc (front) or reg
        const _Float16* hrow = &h1_lds[tt & 1][seg * 72];
        float a0 = back ? wown : wacc[tt & 1][tid];
        float a1 = 0.f, a2 = 0.f, a3 = 0.f;
#pragma unroll
        for (int c2 = 0; c2 < 8; ++c2) {
            float4 hv = *(const float4*)&hrow[c2 << 3];
            a0 = FDOT2(H2(uq[c2].x), H2(hv.x), a0);
            a1 = FDOT2(H2(uq[c2].y), H2(hv.y), a1);
            a2 = FDOT2(H2(uq[c2].z), H2(hv.z), a2);
            a3 = FDOT2(H2(uq[c2].w), H2(hv.w), a3);
        }
        float pr = (a0 + a1) + (a2 + a3);

        // seg butterfly: lanes ±1, ±2
        pr += __shfl_xor(pr, 1);
        pr += __shfl_xor(pr, 2);
        float pre = pr;

        // per-lane activation (gate 3 = tanh, else sigmoid)
        float act;
        if (gate < 3) {
            act = 1.0f / (1.0f + __expf(-pre));
        } else {
            float e = __expf(-2.0f * pre);
            act = 2.0f / (1.0f + e) - 1.0f;
        }

        // gate gather within the wave
        const int bl = (tid & 48) | seg;
        float ig = __shfl(act, bl);
        float fg = __shfl(act, bl | 4);
        float og = __shfl(act, bl | 8);
        float gv = __shfl(act, bl | 12);

        // cell update (16 lanes of dim d compute identically)
        float cn = fg * c_reg + ig * gv;
        c_reg = cn;
        float ec = __expf(-2.0f * cn);
        float hn = og * (2.0f / (1.0f + ec) - 1.0f);

        if (pub) {
            // publish FIRST (critical path), then local h_lds, then out
            unsigned long long pv =
                ((unsigned long long)(unsigned)(tt + 1) << 32) |
                (unsigned long long)__float_as_uint(hn);
            __hip_atomic_store(hbuf + (((size_t)((tt + 1) & 1) * B_SZ + b) * DH + d),
                               pv, __ATOMIC_RELAXED, __HIP_MEMORY_SCOPE_AGENT);
            h1_lds[(tt + 1) & 1][IK16(d)] = (_Float16)hn;   // local dim
            out[((size_t)b * T_SZ + tt) * DH + d] = hn;
        }
        // single-barrier safety (R16 argument), extended:
        //  - wacc[tt&1]: written pre-B1_tt, read post-B1_tt (B1 orders);
        //    next same-parity write is pre-B1_{tt+2}, after B1_{tt+1} which
        //    the reader passed post-read.  - x_lds / h1_lds: as R19/R20.
    }
}

extern "C" void kernel_launch(void* const* d_in, const int* in_sizes, int n_in,
                              void* d_out, int out_size, void* d_ws, size_t ws_size,
                              hipStream_t stream) {
    const float* x    = (const float*)d_in[0];
    const float* W    = (const float*)d_in[1];
    const float* U    = (const float*)d_in[2];
    const float* bias = (const float*)d_in[3];
    float* out = (float*)d_out;

    // ws layout: hbuf 128KB @ 0 (tagged h, parity-double-buffered)
    unsigned long long* hbuf = (unsigned long long*)d_ws;

    // zero hbuf each launch (clean tags; no cross-call state)
    int zero_words = (128 * 1024) / 4;
    zero_ws<<<(zero_words + 255) / 256, 256, 0, stream>>>((unsigned int*)d_ws, zero_words);

    lstm_fused6<<<B_SZ * NW, 512, 0, stream>>>(x, W, U, bias, out, hbuf);
}

// Round 22
// 3011.574 us; speedup vs baseline: 1.0331x; 1.0331x over previous
//
#include <hip/hip_runtime.h>
#include <math.h>

#define B_SZ 32
#define T_SZ 2048
#define DIN 256
#define DH 256
#define FOUR_D 1024

// 8 WGs per batch, 512 threads (R16/R17 skeleton)
// thread -> (dd = tid>>4, gate = (tid>>2)&3, seg = tid&3)
#define NW 8

// padded f16 index: +8 f16 (16B) per 64-elem block
#define IK16(k) ((k) + ((k) >> 6) * 8)
// weight-LDS row stride in f16 elems (264*2=528B -> bank shift 4/row)
#define USTR 264

typedef _Float16 f16x2 __attribute__((ext_vector_type(2)));

#if __has_builtin(__builtin_amdgcn_fdot2)
#define FDOT2(a, b, c) __builtin_amdgcn_fdot2((a), (b), (c), false)
#else
__device__ __forceinline__ float fdot2_emu(f16x2 a, f16x2 b, float c) {
    return c + (float)a[0] * (float)b[0] + (float)a[1] * (float)b[1];
}
#define FDOT2(a, b, c) fdot2_emu((a), (b), (c))
#endif

__device__ __forceinline__ f16x2 H2(float f) {
    union { float f; f16x2 h; } u; u.f = f; return u.h;
}
__device__ __forceinline__ unsigned short F16B(float f) {
    union { _Float16 h; unsigned short u; } cu; cu.h = (_Float16)f; return cu.u;
}
__device__ __forceinline__ float BF16(unsigned short u) {
    union { unsigned short u; _Float16 h; } cu; cu.u = u; return (float)cu.h;
}

__global__ void zero_ws(unsigned int* p, int n) {
    int i = blockIdx.x * blockDim.x + threadIdx.x;
    if (i < n) p[i] = 0u;
}

// Fully-fused single-launch LSTM (R20) with (c,o)-publish:
// slot = [tag32 | o_f16 | c_f16], stored right after the cell FMA — the
// tanh chain (exp+rcp+mul, ~70cy) moves OFF the inter-WG critical path.
// Each poller computes h = o*tanh(c) for its one dim (parallel, shadowed).
// All weights in pinned registers; steady-state LDS = pure broadcast.
__global__ __launch_bounds__(512, 2) void lstm_fused7(
    const float* __restrict__ x, const float* __restrict__ W,
    const float* __restrict__ U, const float* __restrict__ bias,
    float* __restrict__ out, unsigned long long* __restrict__ hbuf)
{
    __shared__ _Float16 u_lds[128 * USTR];   // 67.6 KB f16 U-slice (staging)
    __shared__ _Float16 w_lds[128 * USTR];   // 67.6 KB f16 W-slice (staging)
    __shared__ _Float16 h1_lds[2][288];      // padded f16 h, parity dbuf
    __shared__ _Float16 x_lds[2][288];       // padded f16 x row, parity dbuf

    const int b = blockIdx.x >> 3;     // batch (batch-contiguous)
    const int w = blockIdx.x & 7;      // WG-within-batch
    const int tid = threadIdx.x;
    const int dd = tid >> 4;           // dim within WG: 0..31
    const int gate = (tid >> 2) & 3;   // 0..3
    const int seg = tid & 3;           // K-segment: 0..3 (64 k each)
    const int colg = (gate << 8) + (w << 5) + dd;   // global preact column
    const int d = (w << 5) + dd;       // global dim of this 16-lane group
    const bool pub = (tid & 15) == 0;  // publisher lane for dim d

    // ---- prologue: stage U and W slices to LDS as f16 (derived layout)
    for (int it = 0; it < 64; ++it) {
        int lin = (it << 9) + tid;          // 0..32767
        int row = lin & 127;                // = dd*4 + gate
        int kk = lin >> 7;                  // 0..255
        int gcol = ((row & 3) << 8) + (w << 5) + (row >> 2);
        int sg = kk >> 6;
        int cc = (kk >> 3) & 7;
        int jj = kk & 7;
        int p = ((cc >> 1) << 3) + (sg << 1) + (cc & 1);
        int idx = row * USTR + (p << 3) + jj;
        u_lds[idx] = (_Float16)U[(size_t)kk * FOUR_D + gcol];
        w_lds[idx] = (_Float16)W[(size_t)kk * FOUR_D + gcol];
    }
    // x row 0 -> x_lds[0]; x row 1 -> prefetch regs
    float4 xr = make_float4(0.f, 0.f, 0.f, 0.f);
    if (tid < 64) {
        float4 v0 = *(const float4*)&x[((size_t)b * T_SZ) * DIN + tid * 4];
        _Float16* dst = &x_lds[0][IK16(tid * 4)];
        dst[0] = (_Float16)v0.x; dst[1] = (_Float16)v0.y;
        dst[2] = (_Float16)v0.z; dst[3] = (_Float16)v0.w;
        xr = *(const float4*)&x[((size_t)b * T_SZ + 1) * DIN + tid * 4];
    }
    const float binit = (seg == 0) ? bias[colg] : 0.0f;
    float c_reg = 0.0f;
    __syncthreads();   // u_lds / w_lds / x_lds[0] ready

    // ---- one-time: 8 U chunks AND 8 W chunks -> pinned registers
    const int rowb = (dd * 4 + gate) * USTR;
    float4 uq[8], wq[8];
#pragma unroll
    for (int c2 = 0; c2 < 8; ++c2) {
        int p = ((c2 >> 1) << 3) + (seg << 1) + (c2 & 1);
        uq[c2] = *(const float4*)&u_lds[rowb + (p << 3)];
        wq[c2] = *(const float4*)&w_lds[rowb + (p << 3)];
    }
#pragma unroll
    for (int c2 = 0; c2 < 8; ++c2) {
        asm volatile("" : "+v"(uq[c2].x), "+v"(uq[c2].y),
                          "+v"(uq[c2].z), "+v"(uq[c2].w));
        asm volatile("" : "+v"(wq[c2].x), "+v"(wq[c2].y),
                          "+v"(wq[c2].z), "+v"(wq[c2].w));
    }

    for (int tt = 0; tt < T_SZ; ++tt) {
        // --- pre-poll: stash x_{tt+1} (regs->LDS), prefetch x_{tt+2}
        if (tid < 64) {
            if (tt + 1 < T_SZ) {
                _Float16* dst = &x_lds[(tt + 1) & 1][IK16(tid * 4)];
                dst[0] = (_Float16)xr.x; dst[1] = (_Float16)xr.y;
                dst[2] = (_Float16)xr.z; dst[3] = (_Float16)xr.w;
            }
            if (tt + 2 < T_SZ)
                xr = *(const float4*)&x[((size_t)b * T_SZ + tt + 2) * DIN + tid * 4];
        }

        // --- W-GEMV (h-independent; poll shadow); x via broadcast b128 reads
        const _Float16* xrow = &x_lds[tt & 1][seg * 72];
        float a0 = binit, a1 = 0.f, a2 = 0.f, a3 = 0.f;
#pragma unroll
        for (int c2 = 0; c2 < 8; ++c2) {
            float4 xv = *(const float4*)&xrow[c2 << 3];
            a0 = FDOT2(H2(wq[c2].x), H2(xv.x), a0);
            a1 = FDOT2(H2(wq[c2].y), H2(xv.y), a1);
            a2 = FDOT2(H2(wq[c2].z), H2(xv.z), a2);
            a3 = FDOT2(H2(wq[c2].w), H2(xv.w), a3);
        }

        // --- acquire h_tt: threads 0..255 poll their own dim (tag == tt);
        //     slot carries (c,o) f16 -> poller computes h = o * tanh(c)
        if (tid < DH) {
            const bool local = (tid >> 5) == w;
            if (tt == 0) {
                h1_lds[0][IK16(tid)] = (_Float16)0.0f;
            } else if (!local) {
                const unsigned long long want = (unsigned long long)(unsigned)tt;
                const unsigned long long* slot = hbuf +
                    (((size_t)(tt & 1) * B_SZ + b) * DH + tid);
                unsigned long long v;
                do {
                    v = __hip_atomic_load(slot, __ATOMIC_RELAXED,
                                          __HIP_MEMORY_SCOPE_AGENT);
                } while ((v >> 32) != want);
                float cf = BF16((unsigned short)(v & 0xffffu));
                float of = BF16((unsigned short)((v >> 16) & 0xffffu));
                float e = __expf(-2.0f * cf);
                float hh = of * (2.0f / (1.0f + e) - 1.0f);
                h1_lds[tt & 1][IK16(tid)] = (_Float16)hh;
            }
        }
        __syncthreads();   // B1 (only barrier): h1_lds[tt&1] + x stash done

        // --- U-GEMV from pinned registers; h via broadcast b128 reads
        const _Float16* hrow = &h1_lds[tt & 1][seg * 72];
#pragma unroll
        for (int c2 = 0; c2 < 8; ++c2) {
            float4 hv = *(const float4*)&hrow[c2 << 3];
            a0 = FDOT2(H2(uq[c2].x), H2(hv.x), a0);
            a1 = FDOT2(H2(uq[c2].y), H2(hv.y), a1);
            a2 = FDOT2(H2(uq[c2].z), H2(hv.z), a2);
            a3 = FDOT2(H2(uq[c2].w), H2(hv.w), a3);
        }
        float pr = (a0 + a1) + (a2 + a3);

        // seg butterfly: lanes ±1, ±2
        pr += __shfl_xor(pr, 1);
        pr += __shfl_xor(pr, 2);
        float pre = pr;

        // per-lane activation (gate 3 = tanh, else sigmoid)
        float act;
        if (gate < 3) {
            act = 1.0f / (1.0f + __expf(-pre));
        } else {
            float e = __expf(-2.0f * pre);
            act = 2.0f / (1.0f + e) - 1.0f;
        }

        // gate gather within the wave
        const int bl = (tid & 48) | seg;
        float ig = __shfl(act, bl);
        float fg = __shfl(act, bl | 4);
        float og = __shfl(act, bl | 8);
        float gv = __shfl(act, bl | 12);

        // cell update; PUBLISH (c,o) IMMEDIATELY — tanh chain after
        float cn = fg * c_reg + ig * gv;
        c_reg = cn;

        if (pub) {
            unsigned long long pv =
                ((unsigned long long)(unsigned)(tt + 1) << 32) |
                ((unsigned long long)F16B(og) << 16) |
                (unsigned long long)F16B(cn);
            __hip_atomic_store(hbuf + (((size_t)((tt + 1) & 1) * B_SZ + b) * DH + d),
                               pv, __ATOMIC_RELAXED, __HIP_MEMORY_SCOPE_AGENT);
            // off-critical-path: full-precision h for out[] and local LDS
            float ec = __expf(-2.0f * cn);
            float hn = og * (2.0f / (1.0f + ec) - 1.0f);
            h1_lds[(tt + 1) & 1][IK16(d)] = (_Float16)hn;   // local dim
            out[((size_t)b * T_SZ + tt) * DH + d] = hn;
        }
        // single-barrier safety: identical parity/rendezvous argument to
        // R19/R20 (x_lds, h1_lds both dbuf'd and ordered by B1).
    }
}

extern "C" void kernel_launch(void* const* d_in, const int* in_sizes, int n_in,
                              void* d_out, int out_size, void* d_ws, size_t ws_size,
                              hipStream_t stream) {
    const float* x    = (const float*)d_in[0];
    const float* W    = (const float*)d_in[1];
    const float* U    = (const float*)d_in[2];
    const float* bias = (const float*)d_in[3];
    float* out = (float*)d_out;

    // ws layout: hbuf 128KB @ 0 (tagged (c,o), parity-double-buffered)
    unsigned long long* hbuf = (unsigned long long*)d_ws;

    // zero hbuf each launch (clean tags; no cross-call state)
    int zero_words = (128 * 1024) / 4;
    zero_ws<<<(zero_words + 255) / 256, 256, 0, stream>>>((unsigned int*)d_ws, zero_words);

    lstm_fused7<<<B_SZ * NW, 512, 0, stream>>>(x, W, U, bias, out, hbuf);
}

// Round 23
// 2966.092 us; speedup vs baseline: 1.0490x; 1.0153x over previous
//
#include <hip/hip_runtime.h>
#include <math.h>

#define B_SZ 32
#define T_SZ 2048
#define DIN 256
#define DH 256
#define FOUR_D 1024

// 8 WGs per batch, 512 threads (R16/R17 skeleton)
// thread -> (dd = tid>>4, gate = (tid>>2)&3, seg = tid&3)
#define NW 8

// padded f16 index: +8 f16 (16B) per 64-elem block
#define IK16(k) ((k) + ((k) >> 6) * 8)
// weight-LDS row stride in f16 elems (264*2=528B -> bank shift 4/row)
#define USTR 264

typedef _Float16 f16x2 __attribute__((ext_vector_type(2)));

#if __has_builtin(__builtin_amdgcn_fdot2)
#define FDOT2(a, b, c) __builtin_amdgcn_fdot2((a), (b), (c), false)
#else
__device__ __forceinline__ float fdot2_emu(f16x2 a, f16x2 b, float c) {
    return c + (float)a[0] * (float)b[0] + (float)a[1] * (float)b[1];
}
#define FDOT2(a, b, c) fdot2_emu((a), (b), (c))
#endif

__device__ __forceinline__ f16x2 H2(float f) {
    union { float f; f16x2 h; } u; u.f = f; return u.h;
}

__global__ void zero_ws(unsigned int* p, int n) {
    int i = blockIdx.x * blockDim.x + threadIdx.x;
    if (i < n) p[i] = 0u;
}

// Fully-fused single-launch LSTM (best configuration, = R20):
//  - one dispatch for all T=2048; px pipeline eliminated (x.W computed in
//    the poll shadow from pinned W registers).
//  - U-slice AND W-slice in pinned registers (uq/wq, 64 VGPRs); u_lds/w_lds
//    are prologue-only staging. Steady-state LDS = pure broadcast reads
//    (h row + x row) -> bank conflicts ~1.7e6 (80x below R19).
//  - h exchange: per-dim fp32 tagged agent-scope atomics, parity dbuf
//    (proven optimal across 12 protocol variants, R2..R22).
//  - 1 barrier/step; cell state in registers; wave-local tail via shfl.
// Step time 1.48us = LLC publish->visibility + discovery + skew (~1.1us,
// protocol floor) + in-series GEMV/activation chain (~0.35us).
__global__ __launch_bounds__(512, 2) void lstm_fused5(
    const float* __restrict__ x, const float* __restrict__ W,
    const float* __restrict__ U, const float* __restrict__ bias,
    float* __restrict__ out, unsigned long long* __restrict__ hbuf)
{
    __shared__ _Float16 u_lds[128 * USTR];   // 67.6 KB f16 U-slice (staging)
    __shared__ _Float16 w_lds[128 * USTR];   // 67.6 KB f16 W-slice (staging)
    __shared__ _Float16 h1_lds[2][288];      // padded f16 h, parity dbuf
    __shared__ _Float16 x_lds[2][288];       // padded f16 x row, parity dbuf

    const int b = blockIdx.x >> 3;     // batch (batch-contiguous)
    const int w = blockIdx.x & 7;      // WG-within-batch
    const int tid = threadIdx.x;
    const int dd = tid >> 4;           // dim within WG: 0..31
    const int gate = (tid >> 2) & 3;   // 0..3
    const int seg = tid & 3;           // K-segment: 0..3 (64 k each)
    const int colg = (gate << 8) + (w << 5) + dd;   // global preact column
    const int d = (w << 5) + dd;       // global dim of this 16-lane group
    const bool pub = (tid & 15) == 0;  // publisher lane for dim d

    // ---- prologue: stage U and W slices to LDS as f16 (derived layout)
    for (int it = 0; it < 64; ++it) {
        int lin = (it << 9) + tid;          // 0..32767
        int row = lin & 127;                // = dd*4 + gate
        int kk = lin >> 7;                  // 0..255
        int gcol = ((row & 3) << 8) + (w << 5) + (row >> 2);
        int sg = kk >> 6;
        int cc = (kk >> 3) & 7;
        int jj = kk & 7;
        int p = ((cc >> 1) << 3) + (sg << 1) + (cc & 1);
        int idx = row * USTR + (p << 3) + jj;
        u_lds[idx] = (_Float16)U[(size_t)kk * FOUR_D + gcol];
        w_lds[idx] = (_Float16)W[(size_t)kk * FOUR_D + gcol];
    }
    // x row 0 -> x_lds[0]; x row 1 -> prefetch regs
    float4 xr = make_float4(0.f, 0.f, 0.f, 0.f);
    if (tid < 64) {
        float4 v0 = *(const float4*)&x[((size_t)b * T_SZ) * DIN + tid * 4];
        _Float16* dst = &x_lds[0][IK16(tid * 4)];
        dst[0] = (_Float16)v0.x; dst[1] = (_Float16)v0.y;
        dst[2] = (_Float16)v0.z; dst[3] = (_Float16)v0.w;
        xr = *(const float4*)&x[((size_t)b * T_SZ + 1) * DIN + tid * 4];
    }
    const float binit = (seg == 0) ? bias[colg] : 0.0f;
    float c_reg = 0.0f;
    __syncthreads();   // u_lds / w_lds / x_lds[0] ready

    // ---- one-time: 8 U chunks AND 8 W chunks -> pinned registers
    const int rowb = (dd * 4 + gate) * USTR;
    float4 uq[8], wq[8];
#pragma unroll
    for (int c2 = 0; c2 < 8; ++c2) {
        int p = ((c2 >> 1) << 3) + (seg << 1) + (c2 & 1);
        uq[c2] = *(const float4*)&u_lds[rowb + (p << 3)];
        wq[c2] = *(const float4*)&w_lds[rowb + (p << 3)];
    }
#pragma unroll
    for (int c2 = 0; c2 < 8; ++c2) {
        asm volatile("" : "+v"(uq[c2].x), "+v"(uq[c2].y),
                          "+v"(uq[c2].z), "+v"(uq[c2].w));
        asm volatile("" : "+v"(wq[c2].x), "+v"(wq[c2].y),
                          "+v"(wq[c2].z), "+v"(wq[c2].w));
    }

    for (int tt = 0; tt < T_SZ; ++tt) {
        // --- pre-poll: stash x_{tt+1} (regs->LDS), prefetch x_{tt+2}
        if (tid < 64) {
            if (tt + 1 < T_SZ) {
                _Float16* dst = &x_lds[(tt + 1) & 1][IK16(tid * 4)];
                dst[0] = (_Float16)xr.x; dst[1] = (_Float16)xr.y;
                dst[2] = (_Float16)xr.z; dst[3] = (_Float16)xr.w;
            }
            if (tt + 2 < T_SZ)
                xr = *(const float4*)&x[((size_t)b * T_SZ + tt + 2) * DIN + tid * 4];
        }

        // --- W-GEMV (h-independent; poll shadow); x via broadcast b128 reads
        const _Float16* xrow = &x_lds[tt & 1][seg * 72];
        float a0 = binit, a1 = 0.f, a2 = 0.f, a3 = 0.f;
#pragma unroll
        for (int c2 = 0; c2 < 8; ++c2) {
            float4 xv = *(const float4*)&xrow[c2 << 3];
            a0 = FDOT2(H2(wq[c2].x), H2(xv.x), a0);
            a1 = FDOT2(H2(wq[c2].y), H2(xv.y), a1);
            a2 = FDOT2(H2(wq[c2].z), H2(xv.z), a2);
            a3 = FDOT2(H2(wq[c2].w), H2(xv.w), a3);
        }

        // --- acquire h_tt: threads 0..255 poll their own dim (tag == tt)
        if (tid < DH) {
            const bool local = (tid >> 5) == w;
            if (tt == 0) {
                h1_lds[0][IK16(tid)] = (_Float16)0.0f;
            } else if (!local) {
                const unsigned long long want = (unsigned long long)(unsigned)tt;
                const unsigned long long* slot = hbuf +
                    (((size_t)(tt & 1) * B_SZ + b) * DH + tid);
                unsigned long long v;
                do {
                    v = __hip_atomic_load(slot, __ATOMIC_RELAXED,
                                          __HIP_MEMORY_SCOPE_AGENT);
                } while ((v >> 32) != want);
                h1_lds[tt & 1][IK16(tid)] = (_Float16)__uint_as_float((unsigned)v);
            }
        }
        __syncthreads();   // B1 (only barrier): h1_lds[tt&1] + x stash done

        // --- U-GEMV from pinned registers; h via broadcast b128 reads
        const _Float16* hrow = &h1_lds[tt & 1][seg * 72];
#pragma unroll
        for (int c2 = 0; c2 < 8; ++c2) {
            float4 hv = *(const float4*)&hrow[c2 << 3];
            a0 = FDOT2(H2(uq[c2].x), H2(hv.x), a0);
            a1 = FDOT2(H2(uq[c2].y), H2(hv.y), a1);
            a2 = FDOT2(H2(uq[c2].z), H2(hv.z), a2);
            a3 = FDOT2(H2(uq[c2].w), H2(hv.w), a3);
        }
        float pr = (a0 + a1) + (a2 + a3);

        // seg butterfly: lanes ±1, ±2
        pr += __shfl_xor(pr, 1);
        pr += __shfl_xor(pr, 2);
        float pre = pr;

        // per-lane activation (gate 3 = tanh, else sigmoid)
        float act;
        if (gate < 3) {
            act = 1.0f / (1.0f + __expf(-pre));
        } else {
            float e = __expf(-2.0f * pre);
            act = 2.0f / (1.0f + e) - 1.0f;
        }

        // gate gather within the wave
        const int bl = (tid & 48) | seg;
        float ig = __shfl(act, bl);
        float fg = __shfl(act, bl | 4);
        float og = __shfl(act, bl | 8);
        float gv = __shfl(act, bl | 12);

        // cell update (16 lanes of dim d compute identically)
        float cn = fg * c_reg + ig * gv;
        c_reg = cn;
        float ec = __expf(-2.0f * cn);
        float hn = og * (2.0f / (1.0f + ec) - 1.0f);

        if (pub) {
            // publish FIRST (critical path), then local h_lds, then out
            unsigned long long pv =
                ((unsigned long long)(unsigned)(tt + 1) << 32) |
                (unsigned long long)__float_as_uint(hn);
            __hip_atomic_store(hbuf + (((size_t)((tt + 1) & 1) * B_SZ + b) * DH + d),
                               pv, __ATOMIC_RELAXED, __HIP_MEMORY_SCOPE_AGENT);
            h1_lds[(tt + 1) & 1][IK16(d)] = (_Float16)hn;   // local dim
            out[((size_t)b * T_SZ + tt) * DH + d] = hn;
        }
        // single-barrier safety (R16 argument), extended to x_lds:
        //  - x_lds[(tt+1)&1] written pre-B1_tt, read pre-B1_{tt+1}:  B1_tt orders.
        //  - x_lds[tt&1] read pre-B1_tt, next written pre-B1_{tt+1}: B1_tt orders.
        //  - h1_lds parity: identical to R16/R17.
    }
}

extern "C" void kernel_launch(void* const* d_in, const int* in_sizes, int n_in,
                              void* d_out, int out_size, void* d_ws, size_t ws_size,
                              hipStream_t stream) {
    const float* x    = (const float*)d_in[0];
    const float* W    = (const float*)d_in[1];
    const float* U    = (const float*)d_in[2];
    const float* bias = (const float*)d_in[3];
    float* out = (float*)d_out;

    // ws layout: hbuf 128KB @ 0 (tagged h, parity-double-buffered)
    unsigned long long* hbuf = (unsigned long long*)d_ws;

    // zero hbuf each launch (clean tags; no cross-call state)
    int zero_words = (128 * 1024) / 4;
    zero_ws<<<(zero_words + 255) / 256, 256, 0, stream>>>((unsigned int*)d_ws, zero_words);

    lstm_fused5<<<B_SZ * NW, 512, 0, stream>>>(x, W, U, bias, out, hbuf);
}